// Round 3
// baseline (220.183 us; speedup 1.0000x reference)
//
#include <hip/hip_runtime.h>
#include <hip/hip_bf16.h>

// Centroid update: out[c,:] = 0.3 * mean_{y[i]==c}(embed[i,:]) + 0.7 * centroid[c,:]
//
// R3: counting-sort pipeline (replaces R1/R2's per-class redundant y-scan).
//   K1: histogram counts[c]            (32768 global atomics, trivial)
//   K2: exclusive prefix -> offsets[c], cursor[c]  (one 1024-thread block)
//   K3: scatter row indices -> order[] grouped by class
//   K4: per-class gather (1000 blocks, 256 thr, x8-unrolled row loads = 32KB
//       in flight per block), mean+blend epilogue.
// embed (128 MiB) is read exactly once, fully coalesced 4KB rows -> traffic
// floor ~22us. ws layout: counts@0, offsets@4K, cursor@8K, order@12K (128KB).

#define BATCH       32768
#define EMBED_DIM   1024
#define NUM_CLASSES 1000
#define FACTOR      0.3f

__global__ __launch_bounds__(256) void k1_count(const int* __restrict__ y,
                                                int* __restrict__ counts) {
    const int i = blockIdx.x * 256 + threadIdx.x;
    atomicAdd(&counts[y[i]], 1);
}

__global__ __launch_bounds__(1024) void k2_scan(const int* __restrict__ counts,
                                                int* __restrict__ offsets,
                                                int* __restrict__ cursor) {
    __shared__ int s[1024];
    const int t = threadIdx.x;
    int v = (t < NUM_CLASSES) ? counts[t] : 0;
    s[t] = v;
    __syncthreads();
    // Hillis-Steele inclusive scan over 1024 entries.
    #pragma unroll
    for (int d = 1; d < 1024; d <<= 1) {
        int add = (t >= d) ? s[t - d] : 0;
        __syncthreads();
        s[t] += add;
        __syncthreads();
    }
    const int excl = s[t] - v;   // exclusive prefix
    if (t < NUM_CLASSES) {
        offsets[t] = excl;
        cursor[t]  = excl;
    }
}

__global__ __launch_bounds__(256) void k3_scatter(const int* __restrict__ y,
                                                  int* __restrict__ cursor,
                                                  int* __restrict__ order) {
    const int i = blockIdx.x * 256 + threadIdx.x;
    const int p = atomicAdd(&cursor[y[i]], 1);
    order[p] = i;
}

__global__ __launch_bounds__(256) void k4_gather(const float* __restrict__ embed,
                                                 const float* __restrict__ centroid,
                                                 const int* __restrict__ counts,
                                                 const int* __restrict__ offsets,
                                                 const int* __restrict__ order,
                                                 float* __restrict__ out) {
    const int c   = blockIdx.x;
    const int tid = threadIdx.x;
    const int d   = tid * 4;                 // this thread's dim offset

    const int m    = counts[c];              // scalar (wave-uniform) loads
    const int base = offsets[c];
    const int* __restrict__ rows = order + base;

    float4 acc = make_float4(0.f, 0.f, 0.f, 0.f);
    int j = 0;
    for (; j + 8 <= m; j += 8) {
        const int r0 = rows[j+0], r1 = rows[j+1], r2 = rows[j+2], r3 = rows[j+3];
        const int r4 = rows[j+4], r5 = rows[j+5], r6 = rows[j+6], r7 = rows[j+7];
        const float4 v0 = *reinterpret_cast<const float4*>(embed + (size_t)r0 * EMBED_DIM + d);
        const float4 v1 = *reinterpret_cast<const float4*>(embed + (size_t)r1 * EMBED_DIM + d);
        const float4 v2 = *reinterpret_cast<const float4*>(embed + (size_t)r2 * EMBED_DIM + d);
        const float4 v3 = *reinterpret_cast<const float4*>(embed + (size_t)r3 * EMBED_DIM + d);
        const float4 v4 = *reinterpret_cast<const float4*>(embed + (size_t)r4 * EMBED_DIM + d);
        const float4 v5 = *reinterpret_cast<const float4*>(embed + (size_t)r5 * EMBED_DIM + d);
        const float4 v6 = *reinterpret_cast<const float4*>(embed + (size_t)r6 * EMBED_DIM + d);
        const float4 v7 = *reinterpret_cast<const float4*>(embed + (size_t)r7 * EMBED_DIM + d);
        acc.x += v0.x + v1.x + v2.x + v3.x + v4.x + v5.x + v6.x + v7.x;
        acc.y += v0.y + v1.y + v2.y + v3.y + v4.y + v5.y + v6.y + v7.y;
        acc.z += v0.z + v1.z + v2.z + v3.z + v4.z + v5.z + v6.z + v7.z;
        acc.w += v0.w + v1.w + v2.w + v3.w + v4.w + v5.w + v6.w + v7.w;
    }
    for (; j < m; ++j) {
        const int r = rows[j];
        const float4 v = *reinterpret_cast<const float4*>(embed + (size_t)r * EMBED_DIM + d);
        acc.x += v.x; acc.y += v.y; acc.z += v.z; acc.w += v.w;
    }

    const float inv = 1.0f / (float)m;       // m==0 -> inf -> NaN, matches ref
    const size_t o  = (size_t)c * EMBED_DIM + d;
    const float4 cen = *reinterpret_cast<const float4*>(centroid + o);
    float4 res;
    res.x = FACTOR * (acc.x * inv) + (1.0f - FACTOR) * cen.x;
    res.y = FACTOR * (acc.y * inv) + (1.0f - FACTOR) * cen.y;
    res.z = FACTOR * (acc.z * inv) + (1.0f - FACTOR) * cen.z;
    res.w = FACTOR * (acc.w * inv) + (1.0f - FACTOR) * cen.w;
    *reinterpret_cast<float4*>(out + o) = res;
}

extern "C" void kernel_launch(void* const* d_in, const int* in_sizes, int n_in,
                              void* d_out, int out_size, void* d_ws, size_t ws_size,
                              hipStream_t stream) {
    const float* embed    = (const float*)d_in[0];  // [32768, 1024]
    const int*   y        = (const int*)d_in[1];    // [32768]
    const float* centroid = (const float*)d_in[2];  // [1000, 1024]
    float*       out      = (float*)d_out;          // [1000, 1024]

    // ws layout (512 MB available; we use 140 KB)
    int* counts  = (int*)d_ws;                       // 1024 ints
    int* offsets = counts + 1024;                    // 1024 ints
    int* cursor  = offsets + 1024;                   // 1024 ints
    int* order   = cursor + 1024;                    // 32768 ints

    hipMemsetAsync(counts, 0, 1024 * sizeof(int), stream);   // ws is poisoned 0xAA
    k1_count  <<<BATCH / 256, 256, 0, stream>>>(y, counts);
    k2_scan   <<<1, 1024, 0, stream>>>(counts, offsets, cursor);
    k3_scatter<<<BATCH / 256, 256, 0, stream>>>(y, cursor, order);
    k4_gather <<<NUM_CLASSES, 256, 0, stream>>>(embed, centroid, counts, offsets, order, out);
}